// Round 1
// baseline (1791.824 us; speedup 1.0000x reference)
//
#include <hip/hip_runtime.h>
#include <math.h>

#define N_NODES 50000
#define N_EDGES 400000
#define N_GRAPHS 512
#define TBL 2048
#define EPSBN 1e-5f

__device__ __forceinline__ float softplusf(float x) {
  return fmaxf(x, 0.0f) + log1pf(expf(-fabsf(x)));
}
__device__ __forceinline__ float sigmoidf(float x) {
  return 1.0f / (1.0f + expf(-x));
}
__device__ __forceinline__ void fma4(float4& acc, float s, const float4& w) {
  acc.x = fmaf(s, w.x, acc.x);
  acc.y = fmaf(s, w.y, acc.y);
  acc.z = fmaf(s, w.z, acc.z);
  acc.w = fmaf(s, w.w, acc.w);
}

// ---------------- h = atom @ W_emb + b_emb   [N,92]@[92,64] ----------------
__global__ void k_emb(const float* __restrict__ atom,
                      const float* __restrict__ Wemb,
                      const float* __restrict__ bemb,
                      float* __restrict__ h) {
  __shared__ float sW[92 * 64];   // [k][j] 23.5 KB
  __shared__ float sA[32 * 92];   // [nd][k] 11.5 KB
  const int tid = threadIdx.x;
  for (int i = tid; i < 92 * 64; i += 256) sW[i] = Wemb[i];

  const int t0 = blockIdx.x * 32;
  const int nt = min(32, N_NODES - t0);
  {
    const float* srcp = atom + (size_t)t0 * 92;
    const int tot = nt * 92;
    for (int i = tid; i < tot; i += 256) sA[i] = srcp[i];
  }
  __syncthreads();

  const int col = tid & 63;
  const int ng = tid >> 6;  // node subgroup 0..3 -> nodes ng*8..ng*8+7
  const float bb = bemb[col];
  float acc[8];
#pragma unroll
  for (int i = 0; i < 8; ++i) acc[i] = bb;

  for (int kc = 0; kc < 92; kc += 4) {
    const float w0 = sW[(kc + 0) * 64 + col];
    const float w1 = sW[(kc + 1) * 64 + col];
    const float w2 = sW[(kc + 2) * 64 + col];
    const float w3 = sW[(kc + 3) * 64 + col];
#pragma unroll
    for (int i = 0; i < 8; ++i) {
      const float4 a = *(const float4*)&sA[(ng * 8 + i) * 92 + kc];
      acc[i] = fmaf(a.x, w0, acc[i]);
      acc[i] = fmaf(a.y, w1, acc[i]);
      acc[i] = fmaf(a.z, w2, acc[i]);
      acc[i] = fmaf(a.w, w3, acc[i]);
    }
  }
#pragma unroll
  for (int i = 0; i < 8; ++i) {
    const int n = t0 + ng * 8 + i;
    if (n < N_NODES) h[(size_t)n * 64 + col] = acc[i];
  }
}

// ---------------- PA/PB = h @ [Wi|Wu] split by src/dst halves --------------
__global__ void k_pq(const float* __restrict__ h,
                     const float* __restrict__ Wi_l,
                     const float* __restrict__ Wu_l,
                     float* __restrict__ PA,
                     float* __restrict__ PB) {
  __shared__ float sWA[64 * 128];  // [k][pc] pc: 0..63 Wi-src, 64..127 Wu-src
  __shared__ float sWB[64 * 128];  // [k][pc] pc: 0..63 Wi-dst, 64..127 Wu-dst
  __shared__ float sH[32 * 64];    // [nd][k]
  const int tid = threadIdx.x;

  for (int i = tid; i < 64 * 64; i += 256) {
    const int k = i >> 6, c = i & 63;
    sWA[k * 128 + c]      = Wi_l[k * 64 + c];
    sWA[k * 128 + 64 + c] = Wu_l[k * 64 + c];
    sWB[k * 128 + c]      = Wi_l[(64 + k) * 64 + c];
    sWB[k * 128 + 64 + c] = Wu_l[(64 + k) * 64 + c];
  }
  const int t0 = blockIdx.x * 32;
  const int nt = min(32, N_NODES - t0);
  {
    const float4* srcp = (const float4*)(h + (size_t)t0 * 64);
    const int tot4 = nt * 16;
    float4* dstp = (float4*)sH;
    for (int i = tid; i < tot4; i += 256) dstp[i] = srcp[i];
  }
  __syncthreads();

  const int wave = tid >> 6, lane = tid & 63;
  const float* wcol = (lane < 32) ? (sWA + 4 * lane) : (sWB + 4 * (lane - 32));
  const int jj = (lane < 32) ? 4 * lane : 4 * (lane - 32);
  float* OUTb = (lane < 32) ? PA : PB;

  float4 acc[8];
#pragma unroll
  for (int i = 0; i < 8; ++i) acc[i] = make_float4(0.f, 0.f, 0.f, 0.f);

  for (int kc = 0; kc < 64; kc += 4) {
    const float4 w0 = *(const float4*)(wcol + (kc + 0) * 128);
    const float4 w1 = *(const float4*)(wcol + (kc + 1) * 128);
    const float4 w2 = *(const float4*)(wcol + (kc + 2) * 128);
    const float4 w3 = *(const float4*)(wcol + (kc + 3) * 128);
#pragma unroll
    for (int i = 0; i < 8; ++i) {
      const float4 a = *(const float4*)&sH[(wave * 8 + i) * 64 + kc];
      fma4(acc[i], a.x, w0);
      fma4(acc[i], a.y, w1);
      fma4(acc[i], a.z, w2);
      fma4(acc[i], a.w, w3);
    }
  }
#pragma unroll
  for (int i = 0; i < 8; ++i) {
    const int n = t0 + wave * 8 + i;
    if (n < N_NODES) *(float4*)&OUTb[(size_t)n * 128 + jj] = acc[i];
  }
}

// -------- tbl[t][128] = [ sum_k rbf(d_t,k)*Wi[128+k][:] | same for Wu ] ----
__global__ void k_tbl(const float* __restrict__ Wi_l,
                      const float* __restrict__ Wu_l,
                      float* __restrict__ tbl) {
  const int wave = threadIdx.x >> 6, lane = threadIdx.x & 63;
  const int t = blockIdx.x * (blockDim.x >> 6) + wave;
  if (t >= TBL) return;
  const float d = 8.0f * (float)t / (float)(TBL - 1);
  float gi_ = 0.f, gu_ = 0.f;
#pragma unroll
  for (int k = 0; k < 32; ++k) {
    const float c = 8.0f * (float)k / 31.0f;
    const float dd = d - c;
    const float r = expf(-3.875f * dd * dd);
    gi_ = fmaf(r, Wi_l[(128 + k) * 64 + lane], gi_);
    gu_ = fmaf(r, Wu_l[(128 + k) * 64 + lane], gu_);
  }
  tbl[(size_t)t * 128 + lane] = gi_;
  tbl[(size_t)t * 128 + 64 + lane] = gu_;
}

// ---------------- CSR-by-dst build (once per launch) ----------------------
__global__ void k_deg(const int* __restrict__ dst, int* __restrict__ deg) {
  const int stride = blockDim.x * gridDim.x;
  for (int e = blockIdx.x * blockDim.x + threadIdx.x; e < N_EDGES; e += stride)
    atomicAdd(&deg[dst[e]], 1);
}

// 1 block x 1024 threads. Exclusive scan of deg -> offs[0..N], cursor=offs.
__global__ void k_scan(const int* __restrict__ deg, int* __restrict__ offs,
                       int* __restrict__ cursor) {
  __shared__ int part[1024];
  const int t = threadIdx.x;
  const int CHUNK = (N_NODES + 1023) / 1024;  // 49
  const int base = t * CHUNK;
  int s = 0;
  for (int i = 0; i < CHUNK; ++i) {
    const int idx = base + i;
    if (idx < N_NODES) s += deg[idx];
  }
  part[t] = s;
  __syncthreads();
  for (int off = 1; off < 1024; off <<= 1) {
    int v = (t >= off) ? part[t - off] : 0;
    __syncthreads();
    part[t] += v;
    __syncthreads();
  }
  int run = (t > 0) ? part[t - 1] : 0;
  for (int i = 0; i < CHUNK; ++i) {
    const int idx = base + i;
    if (idx < N_NODES) {
      offs[idx] = run;
      cursor[idx] = run;
      run += deg[idx];
    }
  }
  if (t == 1023) offs[N_NODES] = run;  // = N_EDGES
}

__global__ void k_scatter(const int* __restrict__ src, const int* __restrict__ dst,
                          const float* __restrict__ bond,
                          int* __restrict__ cursor,
                          int* __restrict__ csr_src, float* __restrict__ csr_d) {
  const int stride = blockDim.x * gridDim.x;
  for (int e = blockIdx.x * blockDim.x + threadIdx.x; e < N_EDGES; e += stride) {
    const int p = atomicAdd(&cursor[dst[e]], 1);
    csr_src[p] = src[e];
    csr_d[p] = bond[e];
  }
}

// Per-edge terms that don't involve PB: PA[src] gather + rbf-table lerp.
__device__ __forceinline__ void csr_edge(int k, int lane,
                                         const int* __restrict__ csr_src,
                                         const float* __restrict__ csr_d,
                                         const float* __restrict__ PA,
                                         const float* __restrict__ tbl,
                                         float& pg, float& pu) {
  const int s = csr_src[k];       // wave-uniform -> broadcast load
  const float d = csr_d[k];
  float f = d * ((float)(TBL - 1) / 8.0f);
  f = fminf(fmaxf(f, 0.0f), (float)(TBL - 1));
  int i0 = (int)f;
  if (i0 > TBL - 2) i0 = TBL - 2;
  const float fr = f - (float)i0;
  const float* ta = tbl + (size_t)i0 * 128 + lane;
  const float rg = fmaf(fr, ta[128] - ta[0], ta[0]);
  const float ru = fmaf(fr, ta[192] - ta[64], ta[64]);
  const float* pa = PA + (size_t)s * 128 + lane;
  pg = pa[0] + rg;
  pu = pa[64] + ru;
}

// Pass 1 (dst-centric): column sums / sumsq of gate_pre and upd_pre.
// PB read once per NODE (coalesced), not once per edge.
__global__ void k_stats_csr(const int* __restrict__ offs,
                            const int* __restrict__ csr_src,
                            const float* __restrict__ csr_d,
                            const float* __restrict__ PA,
                            const float* __restrict__ PB,
                            const float* __restrict__ tbl,
                            float* __restrict__ stats) {
  const int wave = threadIdx.x >> 6, lane = threadIdx.x & 63;
  const int wpb = blockDim.x >> 6;
  const int nw = wpb * gridDim.x;
  float sg = 0.f, qg = 0.f, su = 0.f, qu = 0.f;
  for (int n = blockIdx.x * wpb + wave; n < N_NODES; n += nw) {
    const float pbg = PB[(size_t)n * 128 + lane];
    const float pbu = PB[(size_t)n * 128 + 64 + lane];
    const int k0 = offs[n], k1 = offs[n + 1];
    for (int k = k0; k < k1; ++k) {
      float pg, pu;
      csr_edge(k, lane, csr_src, csr_d, PA, tbl, pg, pu);
      const float yg = pg + pbg;
      const float yu = pu + pbu;
      sg += yg; qg = fmaf(yg, yg, qg);
      su += yu; qu = fmaf(yu, yu, qu);
    }
  }
  __shared__ float red[4][4][64];
  red[0][wave][lane] = sg;
  red[1][wave][lane] = qg;
  red[2][wave][lane] = su;
  red[3][wave][lane] = qu;
  __syncthreads();
  const float v = red[wave][0][lane] + red[wave][1][lane] +
                  red[wave][2][lane] + red[wave][3][lane];
  atomicAdd(&stats[wave * 64 + lane], v);
}

__global__ void k_fin_gu(const float* __restrict__ stats,
                         const float* __restrict__ gi_l, const float* __restrict__ bti_l,
                         const float* __restrict__ gu_l, const float* __restrict__ btu_l,
                         float* __restrict__ coefs) {
  const int j = threadIdx.x;
  const float invE = 1.0f / (float)N_EDGES;
  float m = stats[j] * invE;
  float v = stats[64 + j] * invE - m * m;
  float a = gi_l[j] * rsqrtf(v + EPSBN);
  coefs[j] = a;
  coefs[64 + j] = fmaf(-m, a, bti_l[j]);
  m = stats[128 + j] * invE;
  v = stats[192 + j] * invE - m * m;
  a = gu_l[j] * rsqrtf(v + EPSBN);
  coefs[128 + j] = a;
  coefs[192 + j] = fmaf(-m, a, btu_l[j]);
}

// Pass 2 (dst-centric): BN+activations, accumulate msg sum per node in
// REGISTERS, one plain store per node (no atomics), fused agg-stats.
__global__ void k_apply_csr(const int* __restrict__ offs,
                            const int* __restrict__ csr_src,
                            const float* __restrict__ csr_d,
                            const float* __restrict__ PA,
                            const float* __restrict__ PB,
                            const float* __restrict__ tbl,
                            const float* __restrict__ coefs,
                            float* __restrict__ agg,
                            float* __restrict__ stats) {
  const int wave = threadIdx.x >> 6, lane = threadIdx.x & 63;
  const int wpb = blockDim.x >> 6;
  const int nw = wpb * gridDim.x;
  const float ag = coefs[lane], bg = coefs[64 + lane];
  const float au = coefs[128 + lane], bu = coefs[192 + lane];
  float s2 = 0.f, q2 = 0.f;
  for (int n = blockIdx.x * wpb + wave; n < N_NODES; n += nw) {
    const float pbg = PB[(size_t)n * 128 + lane];
    const float pbu = PB[(size_t)n * 128 + 64 + lane];
    const int k0 = offs[n], k1 = offs[n + 1];
    float acc = 0.f;
    for (int k = k0; k < k1; ++k) {
      float pg, pu;
      csr_edge(k, lane, csr_src, csr_d, PA, tbl, pg, pu);
      const float gate = sigmoidf(fmaf(ag, pg + pbg, bg));
      const float upd = softplusf(fmaf(au, pu + pbu, bu));
      acc = fmaf(gate, upd, acc);
    }
    agg[(size_t)n * 64 + lane] = acc;   // plain store, covers deg-0 nodes too
    s2 += acc;
    q2 = fmaf(acc, acc, q2);
  }
  __shared__ float red[2][4][64];
  red[0][wave][lane] = s2;
  red[1][wave][lane] = q2;
  __syncthreads();
  if (wave < 2) {
    const float v = red[wave][0][lane] + red[wave][1][lane] +
                    red[wave][2][lane] + red[wave][3][lane];
    atomicAdd(&stats[256 + wave * 64 + lane], v);
  }
}

__global__ void k_fin_agg(const float* __restrict__ stats,
                          const float* __restrict__ gbn_l, const float* __restrict__ bbn_l,
                          float* __restrict__ coefs) {
  const int j = threadIdx.x;
  const float invN = 1.0f / (float)N_NODES;
  const float m = stats[256 + j] * invN;
  const float v = stats[320 + j] * invN - m * m;
  const float a = gbn_l[j] * rsqrtf(v + EPSBN);
  coefs[256 + j] = a;
  coefs[320 + j] = fmaf(-m, a, bbn_l[j]);
}

// h = softplus(h + BN(agg))
__global__ void k_hupd(float* __restrict__ h, const float* __restrict__ agg,
                       const float* __restrict__ coefs) {
  const int stride = blockDim.x * gridDim.x;
  for (int i = blockIdx.x * blockDim.x + threadIdx.x; i < N_NODES * 64; i += stride) {
    const int j = i & 63;
    const float x = h[i] + fmaf(coefs[256 + j], agg[i], coefs[320 + j]);
    h[i] = softplusf(x);
  }
}

// graph_ids are sorted: contiguous per-wave chunks + local accumulation
// => ~20x fewer pool atomics than per-node atomics.
__global__ void k_pool(const float* __restrict__ h, const int* __restrict__ gid,
                       float* __restrict__ pooled, float* __restrict__ counts) {
  const int lane = threadIdx.x & 63;
  const int wg = blockIdx.x * (blockDim.x >> 6) + (threadIdx.x >> 6);
  const int nwaves = (blockDim.x >> 6) * gridDim.x;
  const int chunk = (N_NODES + nwaves - 1) / nwaves;
  const int n0 = wg * chunk;
  if (n0 >= N_NODES) return;
  const int n1 = min(n0 + chunk, N_NODES);
  int cur = gid[n0];
  float acc = 0.f, cnt = 0.f;
  for (int n = n0; n < n1; ++n) {
    const int g = gid[n];
    if (g != cur) {
      atomicAdd(&pooled[(size_t)cur * 64 + lane], acc);
      if (lane == 0) atomicAdd(&counts[cur], cnt);
      cur = g; acc = 0.f; cnt = 0.f;
    }
    acc += h[(size_t)n * 64 + lane];
    cnt += 1.0f;
  }
  atomicAdd(&pooled[(size_t)cur * 64 + lane], acc);
  if (lane == 0) atomicAdd(&counts[cur], cnt);
}

__global__ void k_final(const float* __restrict__ pooled, const float* __restrict__ counts,
                        const float* __restrict__ Wfc, const float* __restrict__ bfc,
                        const float* __restrict__ Wout, const float* __restrict__ bout,
                        float* __restrict__ out) {
  __shared__ float f1[64];
  __shared__ float red[128];
  const int g = blockIdx.x, t = threadIdx.x;
  if (t < 64) {
    const float c = fmaxf(counts[g], 1.0f);
    f1[t] = softplusf(pooled[(size_t)g * 64 + t] / c);
  }
  __syncthreads();
  float acc = bfc[t];
#pragma unroll
  for (int k = 0; k < 64; ++k) acc = fmaf(f1[k], Wfc[k * 128 + t], acc);
  red[t] = softplusf(softplusf(acc)) * Wout[t];
  __syncthreads();
  for (int s2 = 64; s2 > 0; s2 >>= 1) {
    if (t < s2) red[t] += red[t + s2];
    __syncthreads();
  }
  if (t == 0) out[g] = red[0] + bout[0];
}

extern "C" void kernel_launch(void* const* d_in, const int* in_sizes, int n_in,
                              void* d_out, int out_size, void* d_ws, size_t ws_size,
                              hipStream_t stream) {
  const float* atom = (const float*)d_in[0];
  const float* bond = (const float*)d_in[1];
  const int* src = (const int*)d_in[2];
  const int* dst = (const int*)d_in[3];
  const int* gid = (const int*)d_in[4];
  const float* Wemb = (const float*)d_in[5];
  const float* bemb = (const float*)d_in[6];
  const float* Wi = (const float*)d_in[7];
  // d_in[8] = bi  — cancels under BN (mean-shift), unused
  const float* gi = (const float*)d_in[9];
  const float* bti = (const float*)d_in[10];
  const float* Wu = (const float*)d_in[11];
  // d_in[12] = bu — cancels under BN, unused
  const float* gub = (const float*)d_in[13];
  const float* btu = (const float*)d_in[14];
  const float* gbn = (const float*)d_in[15];
  const float* bbn = (const float*)d_in[16];
  const float* Wfc = (const float*)d_in[17];
  const float* bfc = (const float*)d_in[18];
  const float* Wout = (const float*)d_in[19];
  const float* bout = (const float*)d_in[20];

  // workspace (floats): h N*64 | PA N*128 | PB N*128 | agg N*64 | tbl TBL*128
  //                     | stats 384 | coefs 384 | pooled G*64 | counts G
  //                     | (ints) deg N | offs N+1 | cursor N | csr_src E | csr_d E
  float* h = (float*)d_ws;
  float* PA = h + (size_t)N_NODES * 64;
  float* PB = PA + (size_t)N_NODES * 128;
  float* agg = PB + (size_t)N_NODES * 128;
  float* tbl = agg + (size_t)N_NODES * 64;
  float* stats = tbl + (size_t)TBL * 128;
  float* coefs = stats + 384;
  float* pooled = coefs + 384;
  float* counts = pooled + (size_t)N_GRAPHS * 64;
  int* deg = (int*)(counts + N_GRAPHS);
  int* offs = deg + N_NODES;
  int* cursor = offs + N_NODES + 1;
  int* csr_src = cursor + N_NODES;
  float* csr_d = (float*)(csr_src + N_EDGES);

  const int ntiles = (N_NODES + 31) / 32;  // 1563

  // CSR-by-dst build (independent of h; once per launch)
  (void)hipMemsetAsync(deg, 0, (size_t)N_NODES * sizeof(int), stream);
  k_emb<<<ntiles, 256, 0, stream>>>(atom, Wemb, bemb, h);
  k_deg<<<512, 256, 0, stream>>>(dst, deg);
  k_scan<<<1, 1024, 0, stream>>>(deg, offs, cursor);
  k_scatter<<<512, 256, 0, stream>>>(src, dst, bond, cursor, csr_src, csr_d);

  for (int l = 0; l < 3; ++l) {
    const float* Wi_l = Wi + (size_t)l * 160 * 64;
    const float* Wu_l = Wu + (size_t)l * 160 * 64;
    (void)hipMemsetAsync(stats, 0, 384 * sizeof(float), stream);
    k_pq<<<ntiles, 256, 0, stream>>>(h, Wi_l, Wu_l, PA, PB);
    k_tbl<<<TBL / 4, 256, 0, stream>>>(Wi_l, Wu_l, tbl);
    k_stats_csr<<<2048, 256, 0, stream>>>(offs, csr_src, csr_d, PA, PB, tbl, stats);
    k_fin_gu<<<1, 64, 0, stream>>>(stats, gi + l * 64, bti + l * 64,
                                   gub + l * 64, btu + l * 64, coefs);
    k_apply_csr<<<2048, 256, 0, stream>>>(offs, csr_src, csr_d, PA, PB, tbl,
                                          coefs, agg, stats);
    k_fin_agg<<<1, 64, 0, stream>>>(stats, gbn + l * 64, bbn + l * 64, coefs);
    k_hupd<<<1024, 256, 0, stream>>>(h, agg, coefs);
  }
  (void)hipMemsetAsync(pooled, 0, (size_t)(N_GRAPHS * 64 + N_GRAPHS) * sizeof(float), stream);
  k_pool<<<512, 256, 0, stream>>>(h, gid, pooled, counts);
  k_final<<<N_GRAPHS, 128, 0, stream>>>(pooled, counts, Wfc, bfc, Wout, bout,
                                        (float*)d_out);
}